// Round 6
// baseline (213.939 us; speedup 1.0000x reference)
//
#include <hip/hip_runtime.h>
#include <hip/hip_bf16.h>
#include <math.h>

#define NB 512
#define NS 200
#define NH 256
#define TILE_S 32
#define NTILE 7                  // ceil(200/32); last tile has 8 rows
#define LDSPAD 8
#define LDW (NH + LDSPAD)        // 264 bf16 row stride

// ws float-offset layout
#define OFF_SC 0                                  // scores: 512*200 floats
#define OFF_L  (NB * NS)                          // l: 512*256 floats
#define OFF_UB (OFF_L + NB * NH)                  // Uswz bf16 = 32768 float slots
#define WS_FLOATS_PRE (OFF_UB + (NH * NH) / 2)    // 266240 floats = 1.06 MB
#define WS_FLOATS_MIN (NB * NS)                   // scores only (fallback)

typedef __bf16 bf16x8 __attribute__((ext_vector_type(8)));
typedef float  f32x4  __attribute__((ext_vector_type(4)));

__device__ __forceinline__ float tanh_fast(float x) {
  float xc = fminf(fmaxf(x, -10.f), 10.f);
  float e  = __expf(2.f * xc);
  return (e - 1.f) / (e + 1.f);
}

// ---------------- Kernel 0: precompute l = lastm@W^T (fp32) and swizzled bf16 U ----
// Uswz frag id = ((n_blk*8 + kk)*64 + lane), 8 bf16 each:
// contents U[n_blk*16 + (lane&15)][kk*32 + (lane>>4)*8 + j], j=0..7
__global__ __launch_bounds__(256)
void precompute(const float* __restrict__ lastm, const float* __restrict__ W,
                const float* __restrict__ U,
                float* __restrict__ l_ws, __bf16* __restrict__ Uswz)
{
  const int t = threadIdx.x;
  if (blockIdx.x < NB) {
    const int b = blockIdx.x;
    __shared__ float lm_sm[NH];
    lm_sm[t] = lastm[(size_t)b * NH + t];
    __syncthreads();
    const float4* wrow = (const float4*)(W + (size_t)t * NH);
    const float4* lrow = (const float4*)lm_sm;
    float a0 = 0.f, a1 = 0.f, a2 = 0.f, a3 = 0.f;
#pragma unroll 8
    for (int i = 0; i < NH / 4; ++i) {
      float4 w4 = wrow[i];
      float4 m4 = lrow[i];
      a0 = fmaf(w4.x, m4.x, a0);
      a1 = fmaf(w4.y, m4.y, a1);
      a2 = fmaf(w4.z, m4.z, a2);
      a3 = fmaf(w4.w, m4.w, a3);
    }
    l_ws[(size_t)b * NH + t] = (a0 + a1) + (a2 + a3);
  } else {
    const int id    = (blockIdx.x - NB) * 256 + t;   // 8192 frags
    const int n_blk = id >> 9;
    const int kk    = (id >> 6) & 7;
    const int lane  = id & 63;
    const int row   = n_blk * 16 + (lane & 15);
    const int col   = kk * 32 + (lane >> 4) * 8;
    const float4* s = (const float4*)(U + (size_t)row * NH + col);
    const float4 a = s[0], c = s[1];
    bf16x8 pk;
    pk[0] = (__bf16)a.x; pk[1] = (__bf16)a.y;
    pk[2] = (__bf16)a.z; pk[3] = (__bf16)a.w;
    pk[4] = (__bf16)c.x; pk[5] = (__bf16)c.y;
    pk[6] = (__bf16)c.z; pk[7] = (__bf16)c.w;
    *(bf16x8*)(Uswz + (size_t)id * 8) = pk;
  }
}

// ---------------- Kernel 1: raw scores for one 32-row tile ----------------
// grid = 512*7; block handles tile of rows [tile*32, ...) of batch b.
// No tile loop, no softmax state: stage -> MFMA -> tanh.V reduce -> write scores.
// __launch_bounds__(256,2): R5-proven spill-free codegen regime.
template<bool PRE>
__global__ __launch_bounds__(256, 2)
void scores_kernel(const float* __restrict__ mem,    // [B,S,H]
                   const float* __restrict__ lastm,  // [B,H] (fallback)
                   const float* __restrict__ U,      // [H,H] fp32 (fallback)
                   const float* __restrict__ W,      // [H,H] (fallback)
                   const float* __restrict__ V,      // [H]
                   const float* __restrict__ l_ws,   // [B,H] (PRE)
                   const __bf16* __restrict__ Uswz,  // swizzled bf16 U (PRE)
                   float* __restrict__ scores)       // [B,S]
{
  const int blk  = blockIdx.x;
  const int b    = blk / NTILE;
  const int tile = blk - b * NTILE;
  const int s0   = tile * TILE_S;
  const int rows = min(TILE_S, NS - s0);

  const int t    = threadIdx.x;   // 0..255
  const int wave = t >> 6;        // owns n-cols [wave*64, wave*64+64)
  const int lane = t & 63;
  const int m16  = lane & 15;
  const int quad = lane >> 4;

  __shared__ __align__(16) __bf16 mem_sm[TILE_S][LDW];  // 16.9 KB
  __shared__ float swave_sm[4][TILE_S];
  __shared__ float l_sm[NH];      // fallback only
  __shared__ float lm_sm[NH];     // fallback only

  if (!PRE) {
    lm_sm[t] = lastm[(size_t)b * NH + t];
    __syncthreads();
    const float4* wrow = (const float4*)(W + (size_t)t * NH);
    const float4* lrow = (const float4*)lm_sm;
    float a0 = 0.f, a1 = 0.f, a2 = 0.f, a3 = 0.f;
#pragma unroll 8
    for (int i = 0; i < NH / 4; ++i) {
      float4 w4 = wrow[i];
      float4 m4 = lrow[i];
      a0 = fmaf(w4.x, m4.x, a0);
      a1 = fmaf(w4.y, m4.y, a1);
      a2 = fmaf(w4.z, m4.z, a2);
      a3 = fmaf(w4.w, m4.w, a3);
    }
    l_sm[t] = (a0 + a1) + (a2 + a3);
    __syncthreads();
  }

  // per-thread l/V for this wave's 4 n-fragments
  float l_reg[4], v_reg[4];
#pragma unroll
  for (int nf = 0; nf < 4; ++nf) {
    const int n = wave * 64 + nf * 16 + m16;
    l_reg[nf] = PRE ? l_ws[(size_t)b * NH + n] : l_sm[n];
    v_reg[nf] = V[n];
  }

  // U B-fragments into registers
  bf16x8 u_frag[4][8];
  if (PRE) {
    const __bf16* uw = Uswz + ((size_t)(wave * 4 * 8 * 64) + lane) * 8;
#pragma unroll
    for (int nf = 0; nf < 4; ++nf)
#pragma unroll
      for (int kk = 0; kk < 8; ++kk)
        u_frag[nf][kk] = *(const bf16x8*)(uw + (size_t)((nf * 8 + kk) << 9));
  } else {
#pragma unroll
    for (int nf = 0; nf < 4; ++nf) {
      const int n = wave * 64 + nf * 16 + m16;
      const float* urow = U + (size_t)n * NH;
#pragma unroll
      for (int kk = 0; kk < 8; ++kk) {
        const float4 lo = *(const float4*)(urow + kk * 32 + quad * 8);
        const float4 hi = *(const float4*)(urow + kk * 32 + quad * 8 + 4);
        bf16x8 f;
        f[0] = (__bf16)lo.x; f[1] = (__bf16)lo.y;
        f[2] = (__bf16)lo.z; f[3] = (__bf16)lo.w;
        f[4] = (__bf16)hi.x; f[5] = (__bf16)hi.y;
        f[6] = (__bf16)hi.z; f[7] = (__bf16)hi.w;
        u_frag[nf][kk] = f;
      }
    }
  }

  // ---- stage fp32 -> bf16 LDS (cached loads; mem L3-warm across replays) ----
  const float4* src4 = (const float4*)(mem + ((size_t)b * NS + s0) * NH);
#pragma unroll
  for (int i = 0; i < 4; ++i) {
    const int f2  = i * 256 + t;
    const int row = f2 >> 5;
    const int c8  = (f2 & 31) * 8;
    bf16x8 pk;
    if (row < rows) {
      const float4 a = src4[f2 * 2];
      const float4 c = src4[f2 * 2 + 1];
      pk[0] = (__bf16)a.x; pk[1] = (__bf16)a.y;
      pk[2] = (__bf16)a.z; pk[3] = (__bf16)a.w;
      pk[4] = (__bf16)c.x; pk[5] = (__bf16)c.y;
      pk[6] = (__bf16)c.z; pk[7] = (__bf16)c.w;
    } else {
      pk = (bf16x8)(__bf16)0.f;
    }
    *(bf16x8*)&mem_sm[row][c8] = pk;
  }
  __syncthreads();

  // ---- MFMA: a[s,n] 32 rows x 64 cols per wave ----
  f32x4 acc[2][4];
  const f32x4 fzero = {0.f, 0.f, 0.f, 0.f};
#pragma unroll
  for (int mt = 0; mt < 2; ++mt)
#pragma unroll
    for (int nf = 0; nf < 4; ++nf)
      acc[mt][nf] = fzero;

#pragma unroll
  for (int kk = 0; kk < 8; ++kk) {
    const int c = kk * 32 + quad * 8;
    bf16x8 a0 = *(const bf16x8*)&mem_sm[m16][c];
    bf16x8 a1 = *(const bf16x8*)&mem_sm[16 + m16][c];
#pragma unroll
    for (int nf = 0; nf < 4; ++nf) {
      acc[0][nf] = __builtin_amdgcn_mfma_f32_16x16x32_bf16(a0, u_frag[nf][kk], acc[0][nf], 0, 0, 0);
      acc[1][nf] = __builtin_amdgcn_mfma_f32_16x16x32_bf16(a1, u_frag[nf][kk], acc[1][nf], 0, 0, 0);
    }
  }

  // ---- p = sum_n tanh(a + l[n]) * V[n] over this wave's 64 n ----
  float p[2][4];
#pragma unroll
  for (int mt = 0; mt < 2; ++mt) {
#pragma unroll
    for (int reg = 0; reg < 4; ++reg) {
      float s = 0.f;
#pragma unroll
      for (int nf = 0; nf < 4; ++nf)
        s = fmaf(tanh_fast(acc[mt][nf][reg] + l_reg[nf]), v_reg[nf], s);
      p[mt][reg] = s;
    }
  }
#pragma unroll
  for (int off = 1; off < 16; off <<= 1) {
#pragma unroll
    for (int mt = 0; mt < 2; ++mt)
#pragma unroll
      for (int reg = 0; reg < 4; ++reg)
        p[mt][reg] += __shfl_xor(p[mt][reg], off);
  }
  if (m16 == 0) {
#pragma unroll
    for (int mt = 0; mt < 2; ++mt)
#pragma unroll
      for (int reg = 0; reg < 4; ++reg)
        swave_sm[wave][mt * 16 + quad * 4 + reg] = p[mt][reg];
  }
  __syncthreads();

  if (t < rows)
    scores[(size_t)b * NS + s0 + t] =
        swave_sm[0][t] + swave_sm[1][t] + swave_sm[2][t] + swave_sm[3][t];
}

// ---------------- Kernel 2: exact softmax + pooling + MetaW projection ----------------
// grid = 512, 512 threads (8 waves). Second pass over mem is L3-resident.
__global__ __launch_bounds__(512)
void softmax_pool(const float* __restrict__ scores,  // [B,S]
                  const float* __restrict__ mem,     // [B,S,H]
                  const float* __restrict__ MetaW,   // [4,H]
                  const float* __restrict__ Metab,   // [4]
                  float* __restrict__ out)           // [B,4]
{
  const int b    = blockIdx.x;
  const int t    = threadIdx.x;    // 0..511
  const int wave = t >> 6;         // 0..7
  const int lane = t & 63;

  __shared__ float alpha_sm[NS];
  __shared__ float red_sm[8];
  __shared__ __align__(16) float part_sm[8][NH];
  __shared__ float pooled_sm[NH];

  // load score (threads >= NS hold -inf / 0)
  float sv = (t < NS) ? scores[(size_t)b * NS + t] : -INFINITY;

  // block max
  float wm = sv;
#pragma unroll
  for (int off = 32; off > 0; off >>= 1)
    wm = fmaxf(wm, __shfl_xor(wm, off));
  if (lane == 0) red_sm[wave] = wm;
  __syncthreads();
  float m = red_sm[0];
#pragma unroll
  for (int w = 1; w < 8; ++w) m = fmaxf(m, red_sm[w]);

  // block sum of exp
  float e = (t < NS) ? __expf(sv - m) : 0.f;
  float wsum = e;
#pragma unroll
  for (int off = 32; off > 0; off >>= 1)
    wsum += __shfl_xor(wsum, off);
  __syncthreads();                 // red_sm reuse
  if (lane == 0) red_sm[wave] = wsum;
  __syncthreads();
  float Z = 0.f;
#pragma unroll
  for (int w = 0; w < 8; ++w) Z += red_sm[w];
  const float Zi = 1.f / Z;

  if (t < NS) alpha_sm[t] = e * Zi;
  __syncthreads();

  // pooled: wave w handles rows w, w+8, ... (25 rows); lane owns cols lane*4..lane*4+3
  f32x4 acc4 = {0.f, 0.f, 0.f, 0.f};
  const f32x4* memb = (const f32x4*)(mem + (size_t)b * NS * NH);
  for (int r = wave; r < NS; r += 8) {
    const float a = alpha_sm[r];
    const f32x4 v4 = memb[(size_t)r * (NH / 4) + lane];
    acc4[0] = fmaf(a, v4[0], acc4[0]);
    acc4[1] = fmaf(a, v4[1], acc4[1]);
    acc4[2] = fmaf(a, v4[2], acc4[2]);
    acc4[3] = fmaf(a, v4[3], acc4[3]);
  }
  *(f32x4*)&part_sm[wave][lane * 4] = acc4;
  __syncthreads();

  if (t < NH) {
    float s = 0.f;
#pragma unroll
    for (int w = 0; w < 8; ++w) s += part_sm[w][t];
    pooled_sm[t] = s;
  }
  __syncthreads();

  // projection: wave j (j<4) computes out[b,j]
  if (wave < 4) {
    float s = 0.f;
#pragma unroll
    for (int i = 0; i < 4; ++i) {
      const int h = i * 64 + lane;
      s = fmaf(pooled_sm[h], MetaW[(size_t)wave * NH + h], s);
    }
#pragma unroll
    for (int off = 32; off > 0; off >>= 1)
      s += __shfl_down(s, off);
    if (lane == 0)
      out[b * 4 + wave] = s + Metab[wave];
  }
}

extern "C" void kernel_launch(void* const* d_in, const int* in_sizes, int n_in,
                              void* d_out, int out_size, void* d_ws, size_t ws_size,
                              hipStream_t stream) {
  const float* mem   = (const float*)d_in[0];
  const float* lastm = (const float*)d_in[1];
  const float* U     = (const float*)d_in[2];
  const float* W     = (const float*)d_in[3];
  const float* V     = (const float*)d_in[4];
  const float* MetaW = (const float*)d_in[5];
  const float* Metab = (const float*)d_in[6];
  float* out = (float*)d_out;
  float* ws  = (float*)d_ws;

  float* scores = ws + OFF_SC;

  if (ws_size >= (size_t)WS_FLOATS_PRE * sizeof(float)) {
    float*  l_ws = ws + OFF_L;
    __bf16* Uswz = (__bf16*)(ws + OFF_UB);
    hipLaunchKernelGGL(precompute, dim3(NB + 32), dim3(256), 0, stream,
                       lastm, W, U, l_ws, Uswz);
    hipLaunchKernelGGL(scores_kernel<true>, dim3(NB * NTILE), dim3(256), 0, stream,
                       mem, lastm, U, W, V, l_ws, Uswz, scores);
  } else {
    hipLaunchKernelGGL(scores_kernel<false>, dim3(NB * NTILE), dim3(256), 0, stream,
                       mem, lastm, U, W, V, (const float*)nullptr, (const __bf16*)nullptr, scores);
  }
  hipLaunchKernelGGL(softmax_pool, dim3(NB), dim3(512), 0, stream,
                     scores, mem, MetaW, Metab, out);
}